// Round 1
// baseline (135.636 us; speedup 1.0000x reference)
//
#include <hip/hip_runtime.h>
#include <math.h>

#define LL 8
#define AA 4
#define DD 256
#define SEQN 16384
#define KF 129            // frequencies 0..128 (Hermitian symmetry)
#define NCHUNK 256
#define CLEN 64           // SEQN / NCHUNK
#define NG1 32            // 256 chunk ops -> 32 super ops (groups of 8)
#define NG2 4             // 32 -> 4 (groups of 8)
#define NE 44             // stored complex entries per operator (rows 1..8, l1=0..l)
#define NE1 45            // including implicit row 0 (= e0)

#define IDX(l,l1) ((((l)*((l)+1))/2) + (l1))

// ws layout in floats
#define Q_OFF   0
#define OPS_OFF (32*KF*2)                       // 8256
#define S1_OFF  (OPS_OFF + NCHUNK*NE*KF*2)      // + 2,906,112
#define S2_OFF  (S1_OFF + NG1*NE*KF*2)          // + 363,264
// end = S2_OFF + NG2*NE*KF*2  (~12.7 MB total)

// ---------------- kernel 0: Q[l][c][k] = tanh(logit/2) * DFT_k(softmax(hash_emb[l,c,:])) --------
__global__ __launch_bounds__(256) void kq(const float* __restrict__ hemb,
                                          const float* __restrict__ slog,
                                          float* __restrict__ Q) {
  const int b = blockIdx.x;   // b = l*4 + c
  const int t = threadIdx.x;  // 0..255
  __shared__ float sh[DD];
  __shared__ float red[256];
  float h = hemb[b * DD + t];
  red[t] = h; __syncthreads();
  for (int off = 128; off > 0; off >>= 1) {
    if (t < off) red[t] = fmaxf(red[t], red[t + off]);
    __syncthreads();
  }
  float mx = red[0]; __syncthreads();
  float e = expf(h - mx);
  red[t] = e; __syncthreads();
  for (int off = 128; off > 0; off >>= 1) {
    if (t < off) red[t] += red[t + off];
    __syncthreads();
  }
  float s = red[0];
  sh[t] = e / s;
  __syncthreads();
  if (t < KF) {
    float cr = 0.0f, ci = 0.0f;
    for (int j = 0; j < DD; ++j) {
      const int m = (t * j) & 255;
      const float ang = (float)m * (-0.0245436926061702596754894014319f); // -2*pi/256
      float sn, cs; __sincosf(ang, &sn, &cs);
      const float p = sh[j];
      cr = fmaf(p, cs, cr);
      ci = fmaf(p, sn, ci);
    }
    const float sl = slog[b];
    const float sg = 1.0f / (1.0f + expf(-sl));
    const float q = fmaf(2.0f, sg, -1.0f);   // 2*sigmoid - 1
    Q[(b * KF + t) * 2 + 0] = q * cr;
    Q[(b * KF + t) * 2 + 1] = q * ci;
  }
}

// ---------------- kernel 1: per-(chunk, k) build 64-step transfer operator --------------------
template <int CC>
__device__ __forceinline__ void step_update(float (&Gr)[NE1], float (&Gi)[NE1],
                                            const float (&Qr)[LL][AA], const float (&Qi)[LL][AA],
                                            const float (&z)[LL + 1]) {
#pragma unroll
  for (int l = LL; l >= 1; --l) {          // descending: row l reads OLD row l-1
    const float zl = z[l];
    const float oz = 1.0f - zl;
    const float zqr = zl * Qr[l - 1][CC];
    const float zqi = zl * Qi[l - 1][CC];
    Gr[IDX(l, l)] *= oz;
    Gi[IDX(l, l)] *= oz;
#pragma unroll
    for (int l1 = 0; l1 < l; ++l1) {
      const float hr = Gr[IDX(l - 1, l1)];
      const float hi = Gi[IDX(l - 1, l1)];
      float gr = oz * Gr[IDX(l, l1)];
      float gi = oz * Gi[IDX(l, l1)];
      gr = fmaf(zqr, hr, gr);
      gr = fmaf(-zqi, hi, gr);
      gi = fmaf(zqr, hi, gi);
      gi = fmaf(zqi, hr, gi);
      Gr[IDX(l, l1)] = gr;
      Gi[IDX(l, l1)] = gi;
    }
  }
}

__global__ __launch_bounds__(64) void kchunk(const int* __restrict__ seq,
                                             const float* __restrict__ Q,
                                             float* __restrict__ ops) {
  const int k = blockIdx.y * 64 + threadIdx.x;          // 0..191
  const int kk = (k < KF) ? k : (KF - 1);               // clamp; clamped lanes don't store
  const int p = blockIdx.x;                             // chunk id
  float Qr[LL][AA], Qi[LL][AA];
#pragma unroll
  for (int lc = 0; lc < LL * AA; ++lc) {
    Qr[lc >> 2][lc & 3] = Q[(lc * KF + kk) * 2 + 0];
    Qi[lc >> 2][lc & 3] = Q[(lc * KF + kk) * 2 + 1];
  }
  float Gr[NE1], Gi[NE1];
#pragma unroll
  for (int e = 0; e < NE1; ++e) { Gr[e] = 0.0f; Gi[e] = 0.0f; }
#pragma unroll
  for (int l = 0; l <= LL; ++l) Gr[IDX(l, l)] = 1.0f;   // G = I

  const int base = p * CLEN;
  int c = seq[base];
  for (int s2 = 0; s2 < CLEN; ++s2) {
    const int i = base + s2;
    const int cnext = (s2 + 1 < CLEN) ? seq[i + 1] : 0; // prefetch next symbol
    const float inv = 1.0f / (float)(i + 1);
    float z[LL + 1];
    z[0] = 0.0f;
#pragma unroll
    for (int l = 1; l <= LL; ++l) {
      const float zl = (float)l * inv;
      z[l] = (l <= i + 1) ? zl : 0.0f;
    }
    switch (c) {
      case 0:  step_update<0>(Gr, Gi, Qr, Qi, z); break;
      case 1:  step_update<1>(Gr, Gi, Qr, Qi, z); break;
      case 2:  step_update<2>(Gr, Gi, Qr, Qi, z); break;
      default: step_update<3>(Gr, Gi, Qr, Qi, z); break;
    }
    c = cnext;
  }
  if (k < KF) {
    const size_t b0 = (size_t)p * NE * KF;
#pragma unroll
    for (int e = 1; e < NE1; ++e) {
      ops[(b0 + (size_t)(e - 1) * KF + k) * 2 + 0] = Gr[e];
      ops[(b0 + (size_t)(e - 1) * KF + k) * 2 + 1] = Gi[e];
    }
  }
}

// ---------------- kernel 2: combine 8 consecutive operators (acc = B_j * acc, j ascending) -----
__global__ __launch_bounds__(64) void kcombine(const float* __restrict__ in,
                                               float* __restrict__ out,
                                               int gsize) {
  const int k = blockIdx.y * 64 + threadIdx.x;
  const int kk = (k < KF) ? k : (KF - 1);
  const int g = blockIdx.x;
  float Ar[NE1], Ai[NE1];
  Ar[0] = 1.0f; Ai[0] = 0.0f;
  {
    const size_t b0 = (size_t)(g * gsize) * NE * KF;
#pragma unroll
    for (int e = 1; e < NE1; ++e) {
      Ar[e] = in[(b0 + (size_t)(e - 1) * KF + kk) * 2 + 0];
      Ai[e] = in[(b0 + (size_t)(e - 1) * KF + kk) * 2 + 1];
    }
  }
  for (int j = 1; j < gsize; ++j) {
    float Br[NE1], Bi[NE1];
    Br[0] = 1.0f; Bi[0] = 0.0f;
    const size_t bj = (size_t)(g * gsize + j) * NE * KF;
#pragma unroll
    for (int e = 1; e < NE1; ++e) {
      Br[e] = in[(bj + (size_t)(e - 1) * KF + kk) * 2 + 0];
      Bi[e] = in[(bj + (size_t)(e - 1) * KF + kk) * 2 + 1];
    }
    // acc = B * acc; rows descending so old acc rows < l2 survive; within a row,
    // C[l2][l1] only reads acc[m][l1] with m<=l2 and entries (l2,l1'>l1) not yet written.
#pragma unroll
    for (int l2 = LL; l2 >= 1; --l2) {
#pragma unroll
      for (int l1 = 0; l1 <= l2; ++l1) {
        float cr = 0.0f, ci = 0.0f;
#pragma unroll
        for (int m = l1; m <= l2; ++m) {
          const float br = Br[IDX(l2, m)], bi = Bi[IDX(l2, m)];
          const float ar = Ar[IDX(m, l1)], ai = Ai[IDX(m, l1)];
          cr = fmaf(br, ar, cr); cr = fmaf(-bi, ai, cr);
          ci = fmaf(br, ai, ci); ci = fmaf(bi, ar, ci);
        }
        Ar[IDX(l2, l1)] = cr;
        Ai[IDX(l2, l1)] = ci;
      }
    }
  }
  if (k < KF) {
    const size_t bo = (size_t)g * NE * KF;
#pragma unroll
    for (int e = 1; e < NE1; ++e) {
      out[(bo + (size_t)(e - 1) * KF + k) * 2 + 0] = Ar[e];
      out[(bo + (size_t)(e - 1) * KF + k) * 2 + 1] = Ai[e];
    }
  }
}

// ---------------- kernel 3: apply NG2 ops to state e0, then inverse real DFT ------------------
__global__ __launch_bounds__(256) void kfinal(const float* __restrict__ in,
                                              float* __restrict__ out) {
  const int t = threadIdx.x;
  __shared__ float vr[KF], vi[KF];
  if (t < KF) {
    const int k = t;
    float sr[LL + 1], si[LL + 1];
    sr[0] = 1.0f; si[0] = 0.0f;
#pragma unroll
    for (int l = 1; l <= LL; ++l) { sr[l] = 0.0f; si[l] = 0.0f; }
    for (int g = 0; g < NG2; ++g) {
      float Br[NE1], Bi[NE1];
      const size_t bg = (size_t)g * NE * KF;
#pragma unroll
      for (int e = 1; e < NE1; ++e) {
        Br[e] = in[(bg + (size_t)(e - 1) * KF + k) * 2 + 0];
        Bi[e] = in[(bg + (size_t)(e - 1) * KF + k) * 2 + 1];
      }
#pragma unroll
      for (int l2 = LL; l2 >= 1; --l2) {
        float cr = Br[IDX(l2, 0)];   // G[l2][0] * st[0], st[0] = 1
        float ci = Bi[IDX(l2, 0)];
#pragma unroll
        for (int l1 = 1; l1 <= l2; ++l1) {
          const float br = Br[IDX(l2, l1)], bi = Bi[IDX(l2, l1)];
          cr = fmaf(br, sr[l1], cr); cr = fmaf(-bi, si[l1], cr);
          ci = fmaf(br, si[l1], ci); ci = fmaf(bi, sr[l1], ci);
        }
        sr[l2] = cr; si[l2] = ci;
      }
    }
    vr[k] = sr[LL]; vi[k] = si[LL];
  }
  __syncthreads();
  const int j = t;  // output position
  float sum = vr[0] + ((j & 1) ? -vr[128] : vr[128]);
  for (int k2 = 1; k2 < 128; ++k2) {
    const int m = (j * k2) & 255;
    const float ang = (float)m * 0.0245436926061702596754894014319f;  // +2*pi/256
    float sn, cs; __sincosf(ang, &sn, &cs);
    sum = fmaf(2.0f * vr[k2], cs, sum);
    sum = fmaf(-2.0f * vi[k2], sn, sum);
  }
  out[j] = sum * (1.0f / 256.0f);
}

extern "C" void kernel_launch(void* const* d_in, const int* in_sizes, int n_in,
                              void* d_out, int out_size, void* d_ws, size_t ws_size,
                              hipStream_t stream) {
  (void)in_sizes; (void)n_in; (void)out_size; (void)ws_size;
  const int*   seq  = (const int*)d_in[0];
  const float* hemb = (const float*)d_in[1];
  const float* slog = (const float*)d_in[2];
  float* ws  = (float*)d_ws;
  float* Q   = ws + Q_OFF;
  float* ops = ws + OPS_OFF;
  float* s1  = ws + S1_OFF;
  float* s2  = ws + S2_OFF;
  float* o   = (float*)d_out;

  hipLaunchKernelGGL(kq,       dim3(LL * AA), dim3(256), 0, stream, hemb, slog, Q);
  hipLaunchKernelGGL(kchunk,   dim3(NCHUNK, 3), dim3(64), 0, stream, seq, Q, ops);
  hipLaunchKernelGGL(kcombine, dim3(NG1, 3), dim3(64), 0, stream, ops, s1, 8);
  hipLaunchKernelGGL(kcombine, dim3(NG2, 3), dim3(64), 0, stream, s1, s2, 8);
  hipLaunchKernelGGL(kfinal,   dim3(1), dim3(256), 0, stream, s2, o);
}

// Round 2
// 129.673 us; speedup vs baseline: 1.0460x; 1.0460x over previous
//
#include <hip/hip_runtime.h>
#include <math.h>

#define LL 8
#define AA 4
#define DD 256
#define KF 129            // kq computes frequencies 0..128
#define KH 128            // complex-path frequencies 0..127; k=128 handled as real
#define NCHUNK 512
#define CLEN 32           // 16384 / 512
#define NE 44             // stored complex entries per operator (rows 1..8)
#define NE1 45            // including implicit row 0 (= e0)

#define IDX(l,l1) ((((l)*((l)+1))/2) + (l1))

// ws layout in floats (total ~30.8 MB)
#define Q_OFF   0
#define OPS_OFF (32*KF*2)                    // 8,256
#define S1_OFF  (OPS_OFF + NCHUNK*NE*KH*2)   // + 5,767,168
#define S2_OFF  (S1_OFF + 128*NE*KH*2)       // + 1,441,792
#define S3_OFF  (S2_OFF + 32*NE*KH*2)        // +   360,448
#define R0_OFF  (S3_OFF + 8*NE*KH*2)         // +    90,112
#define R1_OFF  (R0_OFF + NE*NCHUNK)         // +    22,528
#define R2_OFF  (R1_OFF + NE*128)            // +     5,632
#define R3_OFF  (R2_OFF + NE*32)             // +     1,408

// ---------------- kernel 0: Q[l][c][k] = (2*sigmoid(logit)-1) * DFT_k(softmax(hash_emb[l,c,:])) ----
__global__ __launch_bounds__(256) void kq(const float* __restrict__ hemb,
                                          const float* __restrict__ slog,
                                          float* __restrict__ Q) {
  const int b = blockIdx.x;   // b = l*4 + c
  const int t = threadIdx.x;  // 0..255
  __shared__ float sh[DD];
  __shared__ float red[256];
  float h = hemb[b * DD + t];
  red[t] = h; __syncthreads();
  for (int off = 128; off > 0; off >>= 1) {
    if (t < off) red[t] = fmaxf(red[t], red[t + off]);
    __syncthreads();
  }
  float mx = red[0]; __syncthreads();
  float e = expf(h - mx);
  red[t] = e; __syncthreads();
  for (int off = 128; off > 0; off >>= 1) {
    if (t < off) red[t] += red[t + off];
    __syncthreads();
  }
  float s = red[0];
  sh[t] = e / s;
  __syncthreads();
  if (t < KF) {
    float cr = 0.0f, ci = 0.0f;
    for (int j = 0; j < DD; ++j) {
      const int m = (t * j) & 255;
      const float ang = (float)m * (-0.0245436926061702596754894014319f); // -2*pi/256
      float sn, cs; __sincosf(ang, &sn, &cs);
      const float p = sh[j];
      cr = fmaf(p, cs, cr);
      ci = fmaf(p, sn, ci);
    }
    const float sl = slog[b];
    const float sg = 1.0f / (1.0f + expf(-sl));
    const float q = fmaf(2.0f, sg, -1.0f);   // 2*sigmoid - 1
    Q[(b * KF + t) * 2 + 0] = q * cr;
    Q[(b * KF + t) * 2 + 1] = q * ci;
  }
}

// ---------------- complex per-step operator update -------------------------------------------
template <int CC>
__device__ __forceinline__ void step_update(float (&Gr)[NE1], float (&Gi)[NE1],
                                            const float (&Qr)[LL][AA], const float (&Qi)[LL][AA],
                                            const float (&z)[LL + 1]) {
#pragma unroll
  for (int l = LL; l >= 1; --l) {          // descending: row l reads OLD row l-1
    const float zl = z[l];
    const float oz = 1.0f - zl;
    const float zqr = zl * Qr[l - 1][CC];
    const float zqi = zl * Qi[l - 1][CC];
    Gr[IDX(l, l)] *= oz;
    Gi[IDX(l, l)] *= oz;
#pragma unroll
    for (int l1 = 0; l1 < l; ++l1) {
      const float hr = Gr[IDX(l - 1, l1)];
      const float hi = Gi[IDX(l - 1, l1)];
      float gr = oz * Gr[IDX(l, l1)];
      float gi = oz * Gi[IDX(l, l1)];
      gr = fmaf(zqr, hr, gr);
      gr = fmaf(-zqi, hi, gr);
      gi = fmaf(zqr, hi, gi);
      gi = fmaf(zqi, hr, gi);
      Gr[IDX(l, l1)] = gr;
      Gi[IDX(l, l1)] = gi;
    }
  }
}

// ---------------- kernel 1: chunk transfer operators -----------------------------------------
// blocks 0..1023: (chunk p = blk>>1, k = (blk&1)*64 + tid), complex path
// blocks 1024..1031: k=128 real path, lane = chunk
__global__ __launch_bounds__(64) void kchunk(const int* __restrict__ seq,
                                             const float* __restrict__ Q,
                                             float* __restrict__ ops,
                                             float* __restrict__ ops128) {
  const int blk = blockIdx.x;
  const int t = threadIdx.x;
  if (blk < NCHUNK * 2) {
    const int p = blk >> 1;
    const int k = (blk & 1) * 64 + t;    // 0..127
    float Qr[LL][AA], Qi[LL][AA];
    const float2* Q2 = (const float2*)Q;
#pragma unroll
    for (int lc = 0; lc < LL * AA; ++lc) {
      const float2 q = Q2[lc * KF + k];
      Qr[lc >> 2][lc & 3] = q.x;
      Qi[lc >> 2][lc & 3] = q.y;
    }
    float Gr[NE1], Gi[NE1];
#pragma unroll
    for (int e = 0; e < NE1; ++e) { Gr[e] = 0.0f; Gi[e] = 0.0f; }
#pragma unroll
    for (int l = 0; l <= LL; ++l) Gr[IDX(l, l)] = 1.0f;   // G = I

    const int base = p * CLEN;
    for (int s2 = 0; s2 < CLEN; ++s2) {
      const int i = base + s2;
      const int c = seq[i];
      const float inv = 1.0f / (float)(i + 1);
      float z[LL + 1];
      z[0] = 0.0f;
#pragma unroll
      for (int l = 1; l <= LL; ++l) z[l] = (l <= i + 1) ? (float)l * inv : 0.0f;
      switch (c) {
        case 0:  step_update<0>(Gr, Gi, Qr, Qi, z); break;
        case 1:  step_update<1>(Gr, Gi, Qr, Qi, z); break;
        case 2:  step_update<2>(Gr, Gi, Qr, Qi, z); break;
        default: step_update<3>(Gr, Gi, Qr, Qi, z); break;
      }
    }
    float2* O2 = (float2*)ops;
#pragma unroll
    for (int e = 0; e < NE; ++e)
      O2[((size_t)p * NE + e) * KH + k] = make_float2(Gr[e + 1], Gi[e + 1]);
  } else {
    // k = 128 (Nyquist): Q is real there; lane = chunk index
    const int p = (blk - NCHUNK * 2) * 64 + t;   // 0..511
    float Q8[LL][AA];
#pragma unroll
    for (int lc = 0; lc < LL * AA; ++lc) Q8[lc >> 2][lc & 3] = Q[(lc * KF + KH) * 2 + 0];
    float G[NE1];
#pragma unroll
    for (int e = 0; e < NE1; ++e) G[e] = 0.0f;
#pragma unroll
    for (int l = 0; l <= LL; ++l) G[IDX(l, l)] = 1.0f;

    const int base = p * CLEN;
    for (int s2 = 0; s2 < CLEN; ++s2) {
      const int i = base + s2;
      const int c = seq[i];                 // per-lane symbol
      const float inv = 1.0f / (float)(i + 1);
      float z[LL + 1];
      z[0] = 0.0f;
#pragma unroll
      for (int l = 1; l <= LL; ++l) z[l] = (l <= i + 1) ? (float)l * inv : 0.0f;
      float Qs[LL];
#pragma unroll
      for (int l = 0; l < LL; ++l) {
        const float qa = (c & 1) ? Q8[l][1] : Q8[l][0];
        const float qb = (c & 1) ? Q8[l][3] : Q8[l][2];
        Qs[l] = (c & 2) ? qb : qa;
      }
#pragma unroll
      for (int l = LL; l >= 1; --l) {
        const float zl = z[l], oz = 1.0f - zl;
        const float zq = zl * Qs[l - 1];
        G[IDX(l, l)] *= oz;
#pragma unroll
        for (int l1 = 0; l1 < l; ++l1) {
          float g = oz * G[IDX(l, l1)];
          G[IDX(l, l1)] = fmaf(zq, G[IDX(l - 1, l1)], g);
        }
      }
    }
#pragma unroll
    for (int e = 0; e < NE; ++e) ops128[e * NCHUNK + p] = G[e + 1];   // coalesced [e][p]
  }
}

// ---------------- kernel 2: combine 4 consecutive operators ----------------------------------
// blocks 0..ngr*2-1: complex (group g = blk>>1, k = (blk&1)*64+tid)
// remaining blocks: k=128 real, lane = group
__global__ __launch_bounds__(64) void kcomb(const float* __restrict__ in,
                                            float* __restrict__ out,
                                            const float* __restrict__ in128,
                                            float* __restrict__ out128,
                                            int ngr, int n128) {
  const int blk = blockIdx.x;
  const int t = threadIdx.x;
  if (blk < ngr * 2) {
    const int g = blk >> 1;
    const int k = (blk & 1) * 64 + t;
    const float2* I2 = (const float2*)in;
    float Ar[NE1], Ai[NE1];
    Ar[0] = 1.0f; Ai[0] = 0.0f;
#pragma unroll
    for (int e = 0; e < NE; ++e) {
      const float2 v = I2[((size_t)(g * 4 + 0) * NE + e) * KH + k];
      Ar[e + 1] = v.x; Ai[e + 1] = v.y;
    }
    for (int j = 1; j < 4; ++j) {
      float Br[NE1], Bi[NE1];
      Br[0] = 1.0f; Bi[0] = 0.0f;
#pragma unroll
      for (int e = 0; e < NE; ++e) {
        const float2 v = I2[((size_t)(g * 4 + j) * NE + e) * KH + k];
        Br[e + 1] = v.x; Bi[e + 1] = v.y;
      }
      // acc = B * acc (rows descending; within a row ascending l1 — reads precede writes)
#pragma unroll
      for (int l2 = LL; l2 >= 1; --l2) {
#pragma unroll
        for (int l1 = 0; l1 <= l2; ++l1) {
          float cr = 0.0f, ci = 0.0f;
#pragma unroll
          for (int m = l1; m <= l2; ++m) {
            const float br = Br[IDX(l2, m)], bi = Bi[IDX(l2, m)];
            const float ar = Ar[IDX(m, l1)], ai = Ai[IDX(m, l1)];
            cr = fmaf(br, ar, cr); cr = fmaf(-bi, ai, cr);
            ci = fmaf(br, ai, ci); ci = fmaf(bi, ar, ci);
          }
          Ar[IDX(l2, l1)] = cr;
          Ai[IDX(l2, l1)] = ci;
        }
      }
    }
    float2* O2 = (float2*)out;
#pragma unroll
    for (int e = 0; e < NE; ++e)
      O2[((size_t)g * NE + e) * KH + k] = make_float2(Ar[e + 1], Ai[e + 1]);
  } else {
    const int g = (blk - ngr * 2) * 64 + t;
    if (g < n128) {
      const int nin = n128 * 4;
      float A[NE1];
      A[0] = 1.0f;
#pragma unroll
      for (int e = 0; e < NE; ++e) A[e + 1] = in128[e * nin + g * 4 + 0];
      for (int j = 1; j < 4; ++j) {
        float B[NE1];
        B[0] = 1.0f;
#pragma unroll
        for (int e = 0; e < NE; ++e) B[e + 1] = in128[e * nin + g * 4 + j];
#pragma unroll
        for (int l2 = LL; l2 >= 1; --l2) {
#pragma unroll
          for (int l1 = 0; l1 <= l2; ++l1) {
            float cr = 0.0f;
#pragma unroll
            for (int m = l1; m <= l2; ++m) cr = fmaf(B[IDX(l2, m)], A[IDX(m, l1)], cr);
            A[IDX(l2, l1)] = cr;
          }
        }
      }
#pragma unroll
      for (int e = 0; e < NE; ++e) out128[e * n128 + g] = A[e + 1];
    }
  }
}

// ---------------- kernel 3: apply 8 ops to e0, inverse real DFT ------------------------------
__global__ __launch_bounds__(256) void kfinal(const float* __restrict__ in,
                                              const float* __restrict__ in128,
                                              float* __restrict__ out) {
  const int t = threadIdx.x;
  __shared__ float vr[KH + 1], vi[KH + 1];
  if (t < KH) {
    const int k = t;
    const float2* I2 = (const float2*)in;
    float sr[LL + 1], si[LL + 1];
    sr[0] = 1.0f; si[0] = 0.0f;
#pragma unroll
    for (int l = 1; l <= LL; ++l) { sr[l] = 0.0f; si[l] = 0.0f; }
    for (int g = 0; g < 8; ++g) {
      float Br[NE1], Bi[NE1];
#pragma unroll
      for (int e = 0; e < NE; ++e) {
        const float2 v = I2[((size_t)g * NE + e) * KH + k];
        Br[e + 1] = v.x; Bi[e + 1] = v.y;
      }
#pragma unroll
      for (int l2 = LL; l2 >= 1; --l2) {
        float cr = Br[IDX(l2, 0)];   // st[0] = 1
        float ci = Bi[IDX(l2, 0)];
#pragma unroll
        for (int l1 = 1; l1 <= l2; ++l1) {
          const float br = Br[IDX(l2, l1)], bi = Bi[IDX(l2, l1)];
          cr = fmaf(br, sr[l1], cr); cr = fmaf(-bi, si[l1], cr);
          ci = fmaf(br, si[l1], ci); ci = fmaf(bi, sr[l1], ci);
        }
        sr[l2] = cr; si[l2] = ci;
      }
    }
    vr[k] = sr[LL]; vi[k] = si[LL];
  } else if (t == KH) {
    float s[LL + 1];
    s[0] = 1.0f;
#pragma unroll
    for (int l = 1; l <= LL; ++l) s[l] = 0.0f;
    for (int g = 0; g < 8; ++g) {
      float B[NE1];
#pragma unroll
      for (int e = 0; e < NE; ++e) B[e + 1] = in128[e * 8 + g];
#pragma unroll
      for (int l2 = LL; l2 >= 1; --l2) {
        float c = B[IDX(l2, 0)];
#pragma unroll
        for (int l1 = 1; l1 <= l2; ++l1) c = fmaf(B[IDX(l2, l1)], s[l1], c);
        s[l2] = c;
      }
    }
    vr[KH] = s[LL]; vi[KH] = 0.0f;
  }
  __syncthreads();
  const int j = t;  // output position
  float sum = vr[0] + ((j & 1) ? -vr[KH] : vr[KH]);
  for (int k2 = 1; k2 < KH; ++k2) {
    const int m = (j * k2) & 255;
    const float ang = (float)m * 0.0245436926061702596754894014319f;  // +2*pi/256
    float sn, cs; __sincosf(ang, &sn, &cs);
    sum = fmaf(2.0f * vr[k2], cs, sum);
    sum = fmaf(-2.0f * vi[k2], sn, sum);
  }
  out[j] = sum * (1.0f / 256.0f);
}

extern "C" void kernel_launch(void* const* d_in, const int* in_sizes, int n_in,
                              void* d_out, int out_size, void* d_ws, size_t ws_size,
                              hipStream_t stream) {
  (void)in_sizes; (void)n_in; (void)out_size; (void)ws_size;
  const int*   seq  = (const int*)d_in[0];
  const float* hemb = (const float*)d_in[1];
  const float* slog = (const float*)d_in[2];
  float* ws  = (float*)d_ws;
  float* Q   = ws + Q_OFF;
  float* ops = ws + OPS_OFF;
  float* s1  = ws + S1_OFF;
  float* s2  = ws + S2_OFF;
  float* s3  = ws + S3_OFF;
  float* r0  = ws + R0_OFF;
  float* r1  = ws + R1_OFF;
  float* r2  = ws + R2_OFF;
  float* r3  = ws + R3_OFF;
  float* o   = (float*)d_out;

  hipLaunchKernelGGL(kq,     dim3(LL * AA), dim3(256), 0, stream, hemb, slog, Q);
  hipLaunchKernelGGL(kchunk, dim3(NCHUNK * 2 + NCHUNK / 64), dim3(64), 0, stream, seq, Q, ops, r0);
  hipLaunchKernelGGL(kcomb,  dim3(128 * 2 + 2), dim3(64), 0, stream, ops, s1, r0, r1, 128, 128);
  hipLaunchKernelGGL(kcomb,  dim3(32 * 2 + 1), dim3(64), 0, stream, s1, s2, r1, r2, 32, 32);
  hipLaunchKernelGGL(kcomb,  dim3(8 * 2 + 1), dim3(64), 0, stream, s2, s3, r2, r3, 8, 8);
  hipLaunchKernelGGL(kfinal, dim3(1), dim3(256), 0, stream, s3, r3, o);
}